// Round 3
// baseline (286.508 us; speedup 1.0000x reference)
//
#include <hip/hip_runtime.h>
#include <hip/hip_bf16.h>

// Problem constants
#define BATCH 256
#define DIM   2048
#define NMEM  16384   // C_CAM * P
#define PCLS  2048
#define CCAM  8
#define KSEL  50
#define T_INV 14.285714285714285714f   // 1 / 0.07
#define NB2   2048    // tail-histogram bins

typedef __bf16 bf16x8 __attribute__((ext_vector_type(8)));
typedef float  f32x4  __attribute__((ext_vector_type(4)));

static __device__ __forceinline__ unsigned int f2bf(float f) {
  unsigned int u = __float_as_uint(f);
  return (u + 0x7FFFu + ((u >> 16) & 1u)) >> 16;   // RNE truncate to bf16
}
static __device__ __forceinline__ unsigned int pk2(float lo, float hi) {
  return f2bf(lo) | (f2bf(hi) << 16);
}
// tail-window binning
static __device__ __forceinline__ int binw(float x, float lo, float scale) {
  int b = (int)((x - lo) * scale);
  return b > (NB2 - 1) ? (NB2 - 1) : b;
}

// ---------------------------------------------------------------------------
// Kernel 1: row-normalize inputs, cast to bf16.  grid=256 blocks x 256 thr
// ---------------------------------------------------------------------------
__global__ __launch_bounds__(256) void norm_cast_kernel(
    const float* __restrict__ in, unsigned short* __restrict__ xb) {
  __shared__ float red[256];
  const int b = blockIdx.x, t = threadIdx.x;
  const float4* row = (const float4*)(in + (size_t)b * DIM);
  float4 a0 = row[t];
  float4 a1 = row[t + 256];
  float ss = a0.x*a0.x + a0.y*a0.y + a0.z*a0.z + a0.w*a0.w
           + a1.x*a1.x + a1.y*a1.y + a1.z*a1.z + a1.w*a1.w;
  red[t] = ss; __syncthreads();
  for (int s = 128; s > 0; s >>= 1) { if (t < s) red[t] += red[t + s]; __syncthreads(); }
  const float rn = rsqrtf(red[0]);
  ushort4 o0, o1;
  o0.x = (unsigned short)f2bf(a0.x*rn); o0.y = (unsigned short)f2bf(a0.y*rn);
  o0.z = (unsigned short)f2bf(a0.z*rn); o0.w = (unsigned short)f2bf(a0.w*rn);
  o1.x = (unsigned short)f2bf(a1.x*rn); o1.y = (unsigned short)f2bf(a1.y*rn);
  o1.z = (unsigned short)f2bf(a1.z*rn); o1.w = (unsigned short)f2bf(a1.w*rn);
  *(ushort4*)&xb[(size_t)b * DIM + t * 4]         = o0;
  *(ushort4*)&xb[(size_t)b * DIM + (t + 256) * 4] = o1;
}

// ---------------------------------------------------------------------------
// Kernel 2: logits = x(bf16) @ tempV^T
// BM=128, BN=32, BK=32. 256 thr = 4 waves, wave = 32x32 output (2x2 frags).
// Round-2 post-mortem: all pipes idle (Mfma 8%, VALU 11%, HBM 22%) at 34%
// occupancy -> per-iteration vmcnt(0)-drain latency is structural, not a
// concurrency problem. Changes:
//  - A is NOT staged in LDS: waves own disjoint rows, X is L2-resident on
//    every XCD, so LDS staging of A saved no traffic. A-frags are loaded
//    directly (16B/lane contiguous) into named registers one tile ahead.
//  - B only in LDS: 2 KB bf16 tile, DOUBLE-buffered, ONE barrier per
//    K-step. B float4 loaded 2 phases before its ds_write (~600cy cover).
//  - BK=32: Bs rows = 64 B -> ds_read_b128 frag reads naturally
//    bank-balanced (8 lanes / 4-bank group = the 1KB minimum).
//  - grid dim3(512,2), x = n-tile: the 2 m-blocks sharing a V-row are 512
//    apart -> same XCD under round-robin -> 2nd read is an L2 hit.
// ---------------------------------------------------------------------------
#define BM 128
#define BN 32
#define BK 32
#define NT (DIM / BK)   // 64 k-tiles

__global__ __launch_bounds__(256, 2) void gemm_kernel(
    const unsigned short* __restrict__ X,   // [256][2048] bf16
    const float* __restrict__ V,            // [16384][2048] fp32
    float* __restrict__ C) {                // [256][16384] fp32
  __shared__ unsigned short Bs0[BN * BK];   // 2 KB
  __shared__ unsigned short Bs1[BN * BK];   // 2 KB
  const int t  = threadIdx.x;
  const int n0 = blockIdx.x * BN;           // x = n-tile (XCD pairing)
  const int m0 = blockIdx.y * BM;
  const int lane = t & 63;
  const int w    = t >> 6;
  const int wm   = w * 32;                  // wave's 32-row m sub-tile

  f32x4 acc[2][2];
#pragma unroll
  for (int i = 0; i < 2; i++)
#pragma unroll
    for (int j = 0; j < 2; j++) acc[i][j] = (f32x4){0.f, 0.f, 0.f, 0.f};

  // B staging: thread t -> row t>>3 (0..31), 4 floats at col (t&7)*4.
  // Per wave instr: 8 rows x 128 B contiguous — fully coalesced.
  const int br = t >> 3;
  const int bc = (t & 7) * 4;               // elem col (4 bf16 = 8 B out)
  const float* Vp = V + (size_t)(n0 + br) * DIM + bc;
  unsigned short* BW0 = &Bs0[br * BK + bc];
  unsigned short* BW1 = &Bs1[br * BK + bc];

  // A-frag addressing (direct from global, L2-resident):
  // lane (q=lane>>4, r=lane&15) holds A[row=wm+16i+r][k = kt*32 + 8q..+7]
  const int fr = lane & 15;
  const int fq8 = (lane >> 4) * 8;
  const unsigned short* Ap = X + (size_t)(m0 + wm + fr) * DIM + fq8;

  // ---- prologue: tile0 -> Bs0; frag/stage prefetch ----
  {
    float4 bt = *(const float4*)Vp;                 // tile 0
    uint2 p; p.x = pk2(bt.x, bt.y); p.y = pk2(bt.z, bt.w);
    *(uint2*)BW0 = p;
  }
  float4 bO = *(const float4*)(Vp + 1 * BK);        // tile 1 (write @ phase 0)
  float4 bE = *(const float4*)(Vp + 2 * BK);        // tile 2 (write @ phase 1)
  bf16x8 aE0 = *(const bf16x8*)(Ap);                // tile 0 frags
  bf16x8 aE1 = *(const bf16x8*)(Ap + 16 * DIM);
  bf16x8 aO0 = *(const bf16x8*)(Ap + BK);           // tile 1 frags
  bf16x8 aO1 = *(const bf16x8*)(Ap + 16 * DIM + BK);
  __syncthreads();

#pragma unroll 1
  for (int s = 0; s < NT / 2; ++s) {
    const int te = 2 * s;

    // ======== phase even: compute tile te from Bs0, write te+1 -> Bs1 ====
    {
      uint2 p; p.x = pk2(bO.x, bO.y); p.y = pk2(bO.z, bO.w);
      *(uint2*)BW1 = p;                             // tile te+1
    }
    {
      const int kb = min(te + 3, NT - 1) * BK;      // reload bO: tile te+3
      bO = *(const float4*)(Vp + kb);
      const int ka = min(te + 2, NT - 1) * BK;      // A frags: tile te+2
      bf16x8 n0f = *(const bf16x8*)(Ap + ka);
      bf16x8 n1f = *(const bf16x8*)(Ap + 16 * DIM + ka);
      bf16x8 bF0 = *(const bf16x8*)&Bs0[fr * BK + fq8];
      bf16x8 bF1 = *(const bf16x8*)&Bs0[(16 + fr) * BK + fq8];
      acc[0][0] = __builtin_amdgcn_mfma_f32_16x16x32_bf16(aE0, bF0, acc[0][0], 0, 0, 0);
      acc[0][1] = __builtin_amdgcn_mfma_f32_16x16x32_bf16(aE0, bF1, acc[0][1], 0, 0, 0);
      acc[1][0] = __builtin_amdgcn_mfma_f32_16x16x32_bf16(aE1, bF0, acc[1][0], 0, 0, 0);
      acc[1][1] = __builtin_amdgcn_mfma_f32_16x16x32_bf16(aE1, bF1, acc[1][1], 0, 0, 0);
      aE0 = n0f; aE1 = n1f;
    }
    __syncthreads();

    // ======== phase odd: compute tile te+1 from Bs1, write te+2 -> Bs0 ===
    {
      uint2 p; p.x = pk2(bE.x, bE.y); p.y = pk2(bE.z, bE.w);
      *(uint2*)BW0 = p;                             // tile te+2
    }
    {
      const int kb = min(te + 4, NT - 1) * BK;      // reload bE: tile te+4
      bE = *(const float4*)(Vp + kb);
      const int ka = min(te + 3, NT - 1) * BK;      // A frags: tile te+3
      bf16x8 n0f = *(const bf16x8*)(Ap + ka);
      bf16x8 n1f = *(const bf16x8*)(Ap + 16 * DIM + ka);
      bf16x8 bF0 = *(const bf16x8*)&Bs1[fr * BK + fq8];
      bf16x8 bF1 = *(const bf16x8*)&Bs1[(16 + fr) * BK + fq8];
      acc[0][0] = __builtin_amdgcn_mfma_f32_16x16x32_bf16(aO0, bF0, acc[0][0], 0, 0, 0);
      acc[0][1] = __builtin_amdgcn_mfma_f32_16x16x32_bf16(aO0, bF1, acc[0][1], 0, 0, 0);
      acc[1][0] = __builtin_amdgcn_mfma_f32_16x16x32_bf16(aO1, bF0, acc[1][0], 0, 0, 0);
      acc[1][1] = __builtin_amdgcn_mfma_f32_16x16x32_bf16(aO1, bF1, acc[1][1], 0, 0, 0);
      aO0 = n0f; aO1 = n1f;
    }
    __syncthreads();
  }

  // epilogue: C/D layout col=lane&15, row=(lane>>4)*4+reg  [m89/m91 verified]
  const int cr = (lane >> 4) * 4;
  const int cc = lane & 15;
#pragma unroll
  for (int i = 0; i < 2; i++)
#pragma unroll
    for (int j = 0; j < 2; j++)
#pragma unroll
      for (int r = 0; r < 4; r++)
        C[(size_t)(m0 + wm + i * 16 + cr + r) * NMEM + (n0 + j * 16 + cc)] =
            acc[i][j][r];
}

// ---------------------------------------------------------------------------
// Kernel 3: per-row losses. One block of 1024 thr per sample.
// REGISTER-RESIDENT row: 16 floats/thread in 4 named float4s (statically
// unrolled) — one global read of the row instead of 3.
//  pass 1: masked row max + intra exp-sum over own bank (fused)
//  pass 2: tail histogram over [vmax-W, vmax], 2048 bins; widening fallback
//  pass 3: sum exp over bins > boundary; boundary bin resolved exactly
// ---------------------------------------------------------------------------
__global__ __launch_bounds__(1024) void row_loss_kernel(
    const float* __restrict__ logits,
    const int* __restrict__ labels, const int* __restrict__ cams,
    float* __restrict__ ce_out, float* __restrict__ lossk_out) {
  __shared__ float ovs[CCAM];
  __shared__ float wredA[16], wredB[16];
  __shared__ int   hist[NB2];       // 8 KB
  __shared__ int   pint[256];
  __shared__ float bl[512];
  __shared__ int   bcount;
  __shared__ int   bstar_s, cabove_s, totwin_s;
  __shared__ float vmax_s;

  const int b = blockIdx.x, t = threadIdx.x;
  const int lane = t & 63, wid = t >> 6;
  const int cam = cams[b], label = labels[b];
  const float* row = logits + (size_t)b * NMEM;

  if (t < CCAM) ovs[t] = row[t * PCLS + label];

  float4 rr[4];
#pragma unroll
  for (int i = 0; i < 4; i++) rr[i] = *(const float4*)(row + (size_t)(t + 1024 * i) * 4);

  // ---- pass 1: masked max + intra exp-sum (own bank, unmasked) ----
  float vmax = -1e30f, Si = 0.f;
#pragma unroll
  for (int i = 0; i < 4; i++) {
    const int base = (t + 1024 * i) * 4;
    const float xs[4] = {rr[i].x, rr[i].y, rr[i].z, rr[i].w};
#pragma unroll
    for (int e = 0; e < 4; e++) {
      const int n = base + e;
      const float x = xs[e];
      if ((n >> 11) == cam) Si += __expf(x * T_INV);
      if ((n & (PCLS - 1)) != label) vmax = fmaxf(vmax, x);
    }
  }
#pragma unroll
  for (int off = 32; off > 0; off >>= 1) {
    vmax = fmaxf(vmax, __shfl_down(vmax, off));
    Si  += __shfl_down(Si, off);
  }
  if (lane == 0) { wredA[wid] = vmax; wredB[wid] = Si; }
  __syncthreads();
  if (t == 0) {
    float m = -1e30f, s = 0.f;
    for (int i = 0; i < 16; i++) { m = fmaxf(m, wredA[i]); s += wredB[i]; }
    vmax_s = m;
    ce_out[b] = logf(s) - ovs[cam] * T_INV;
    bcount = 0;
  }
  __syncthreads();

  // ---- pass 2: tail histogram with widening fallback ----
  float W = 0.0625f;
  float lo = 0.f, scale = 0.f;
  for (int att = 0; att < 6; ++att) {
    __syncthreads();
    for (int i = t; i < NB2; i += 1024) hist[i] = 0;
    __syncthreads();
    lo = vmax_s - W; scale = (float)NB2 / W;
#pragma unroll
    for (int i = 0; i < 4; i++) {
      const int base = (t + 1024 * i) * 4;
      const float xs[4] = {rr[i].x, rr[i].y, rr[i].z, rr[i].w};
#pragma unroll
      for (int e = 0; e < 4; e++) {
        const int n = base + e;
        const float x = xs[e];
        if (((n & (PCLS - 1)) != label) && x >= lo)
          atomicAdd(&hist[binw(x, lo, scale)], 1);
      }
    }
    __syncthreads();
    if (t < 256) {
      int ps = 0;
#pragma unroll
      for (int i = 0; i < 8; i++) ps += hist[t * 8 + i];
      pint[t] = ps;
    }
    __syncthreads();
    if (t == 0) {
      int tot = 0;
      for (int i = 0; i < 256; i++) tot += pint[i];
      totwin_s = tot;
      if (tot >= KSEL) {
        int cum = 0, bstar = 0, cab = 0;
        for (int tc = 255; tc >= 0; tc--) {
          if (cum + pint[tc] >= KSEL) {
            for (int bi = tc * 8 + 7; bi >= tc * 8; bi--) {
              int h = hist[bi];
              if (cum + h >= KSEL) { bstar = bi; cab = cum; break; }
              cum += h;
            }
            break;
          }
          cum += pint[tc];
        }
        bstar_s = bstar; cabove_s = cab;
      }
    }
    __syncthreads();
    if (totwin_s >= KSEL) break;
    W *= 8.f;
  }
  const int bstar = bstar_s;

  // ---- pass 3: sum exp over bins > b*, collect boundary bin ----
  float S2 = 0.f;
#pragma unroll
  for (int i = 0; i < 4; i++) {
    const int base = (t + 1024 * i) * 4;
    const float xs[4] = {rr[i].x, rr[i].y, rr[i].z, rr[i].w};
#pragma unroll
    for (int e = 0; e < 4; e++) {
      const int n = base + e;
      const float x = xs[e];
      if (((n & (PCLS - 1)) != label) && x >= lo) {
        const int bin = binw(x, lo, scale);
        if (bin > bstar) S2 += __expf(x * T_INV);
        else if (bin == bstar) {
          int p = atomicAdd(&bcount, 1);
          if (p < 512) bl[p] = x;
        }
      }
    }
  }
#pragma unroll
  for (int off = 32; off > 0; off >>= 1) S2 += __shfl_down(S2, off);
  if (lane == 0) wredB[wid] = S2;
  __syncthreads();

  if (t == 0) {
    float S2tot = 0.f;
    for (int i = 0; i < 16; i++) S2tot += wredB[i];
    const int need = KSEL - cabove_s;
    const int bc = min(bcount, 512);
    for (int r = 0; r < need; r++) {         // exact top-(need) of boundary bin
      float mx = -1e30f; int mi = 0;
      for (int i = 0; i < bc; i++) if (bl[i] > mx) { mx = bl[i]; mi = i; }
      S2tot += __expf(mx * T_INV);
      bl[mi] = -1e30f;
    }
    float sumo = 0.f;
#pragma unroll
    for (int c = 0; c < CCAM; c++) { S2tot += __expf(ovs[c] * T_INV); sumo += ovs[c]; }
    lossk_out[b] = logf(S2tot) - (sumo * T_INV) * (1.0f / CCAM);
  }
}

// ---------------------------------------------------------------------------
// Kernel 4: deterministic per-camera segment means -> 2 scalars.
// ---------------------------------------------------------------------------
__global__ __launch_bounds__(256) void finalize_kernel(
    const float* __restrict__ ce, const float* __restrict__ lossk,
    const int* __restrict__ cams, float* __restrict__ out) {
  __shared__ float ce_s[BATCH], lk_s[BATCH];
  __shared__ int   cam_s[BATCH];
  __shared__ float si[CCAM], sk[CCAM], cnt[CCAM];
  const int t = threadIdx.x;
  ce_s[t]  = ce[t];
  lk_s[t]  = lossk[t];
  cam_s[t] = cams[t];
  __syncthreads();
  if (t < CCAM) {
    float a = 0.f, b = 0.f; int n = 0;
    for (int i = 0; i < BATCH; i++) {
      if (cam_s[i] == t) { a += ce_s[i]; b += lk_s[i]; n++; }
    }
    si[t] = a; sk[t] = b; cnt[t] = (float)n;
  }
  __syncthreads();
  if (t == 0) {
    float li = 0.f, lk = 0.f;
    for (int c = 0; c < CCAM; c++) {
      if (cnt[c] > 0.f) { li += si[c] / cnt[c]; lk += sk[c] / cnt[c]; }
    }
    out[0] = li;
    out[1] = 0.5f * lk;
  }
}

// ---------------------------------------------------------------------------
extern "C" void kernel_launch(void* const* d_in, const int* in_sizes, int n_in,
                              void* d_out, int out_size, void* d_ws, size_t ws_size,
                              hipStream_t stream) {
  const float* inputs = (const float*)d_in[0];   // [256][2048]
  const int*   labels = (const int*)d_in[1];     // [256]
  const int*   cams   = (const int*)d_in[2];     // [256]
  const float* tempV  = (const float*)d_in[3];   // [16384][2048]
  float* out = (float*)d_out;

  char* ws = (char*)d_ws;
  unsigned short* xb  = (unsigned short*)ws;                       // 1 MB
  float* logits       = (float*)(ws + (1u << 20));                 // 16 MB
  float* ce           = (float*)(ws + (1u << 20) + (16u << 20));   // 1 KB
  float* lossk        = (float*)(ws + (1u << 20) + (16u << 20) + 1024);

  norm_cast_kernel<<<BATCH, 256, 0, stream>>>(inputs, xb);
  gemm_kernel<<<dim3(NMEM / BN, BATCH / BM), 256, 0, stream>>>(xb, tempV, logits);
  row_loss_kernel<<<BATCH, 1024, 0, stream>>>(logits, labels, cams, ce, lossk);
  finalize_kernel<<<1, 256, 0, stream>>>(ce, lossk, cams, out);
}

// Round 4
// 270.253 us; speedup vs baseline: 1.0601x; 1.0601x over previous
//
#include <hip/hip_runtime.h>
#include <hip/hip_bf16.h>

// Problem constants
#define BATCH 256
#define DIM   2048
#define NMEM  16384   // C_CAM * P
#define PCLS  2048
#define CCAM  8
#define KSEL  50
#define T_INV 14.285714285714285714f   // 1 / 0.07
#define NB2   2048    // tail-histogram bins

typedef __bf16 bf16x8 __attribute__((ext_vector_type(8)));
typedef float  f32x4  __attribute__((ext_vector_type(4)));

static __device__ __forceinline__ unsigned int f2bf(float f) {
  unsigned int u = __float_as_uint(f);
  return (u + 0x7FFFu + ((u >> 16) & 1u)) >> 16;   // RNE truncate to bf16
}
static __device__ __forceinline__ unsigned int pk2(float lo, float hi) {
  return f2bf(lo) | (f2bf(hi) << 16);
}
// tail-window binning
static __device__ __forceinline__ int binw(float x, float lo, float scale) {
  int b = (int)((x - lo) * scale);
  return b > (NB2 - 1) ? (NB2 - 1) : b;
}

// Packed-A addressing: elem index of (row r, col c) in MFMA-fragment order.
// frag tile: mf = r>>4 (16 rows), kc = c>>5 (32 cols); within tile lane
// l = (r&15) | (((c>>3)&3)<<4) holds 8 consecutive c's. One wave frag load
// = 64 lanes x 16B contiguous = 1KB.
static __device__ __forceinline__ size_t pa_idx(int r, int c) {
  return (size_t)(r >> 4) * (size_t)(64 * 8 * (DIM / 32))   // 32768 per mf
       + (size_t)(c >> 5) * 512
       + (size_t)(((r & 15) | (((c >> 3) & 3) << 4))) * 8
       + (size_t)(c & 7);
}

// ---------------------------------------------------------------------------
// Kernel 1: row-normalize inputs, cast to bf16, write A PRE-PACKED in MFMA
// fragment order (consumed directly by gemm A-frag loads, 1KB/wave-instr).
// ---------------------------------------------------------------------------
__global__ __launch_bounds__(256) void norm_cast_kernel(
    const float* __restrict__ in, unsigned short* __restrict__ xpk) {
  __shared__ float red[256];
  const int b = blockIdx.x, t = threadIdx.x;
  const float4* row = (const float4*)(in + (size_t)b * DIM);
  float4 a0 = row[t];
  float4 a1 = row[t + 256];
  float ss = a0.x*a0.x + a0.y*a0.y + a0.z*a0.z + a0.w*a0.w
           + a1.x*a1.x + a1.y*a1.y + a1.z*a1.z + a1.w*a1.w;
  red[t] = ss; __syncthreads();
  for (int s = 128; s > 0; s >>= 1) { if (t < s) red[t] += red[t + s]; __syncthreads(); }
  const float rn = rsqrtf(red[0]);
  ushort4 o0, o1;
  o0.x = (unsigned short)f2bf(a0.x*rn); o0.y = (unsigned short)f2bf(a0.y*rn);
  o0.z = (unsigned short)f2bf(a0.z*rn); o0.w = (unsigned short)f2bf(a0.w*rn);
  o1.x = (unsigned short)f2bf(a1.x*rn); o1.y = (unsigned short)f2bf(a1.y*rn);
  o1.z = (unsigned short)f2bf(a1.z*rn); o1.w = (unsigned short)f2bf(a1.w*rn);
  // packed stores: c = 4t and 4(t+256); (c&7) in {0,4} -> 8B-aligned ushort4
  *(ushort4*)&xpk[pa_idx(b, 4 * t)]         = o0;
  *(ushort4*)&xpk[pa_idx(b, 4 * (t + 256))] = o1;
}

// ---------------------------------------------------------------------------
// Kernel 2: logits = x(bf16) @ tempV^T — BARRIER-FREE K-loop.
// Rounds 0-3 post-mortem: every per-K-step-barrier structure caps V-stream
// at 1.4-1.8 TB/s (whole-CU vmcnt drains), independent of occupancy.
// New structure: block = 16 V-rows x FULL K, LDS-resident as 4 quarter
// panels (2 x 16.5KB buffers). Per quarter: next quarter's 8 float4/thread
// global loads are issued spread through the 16 MFMA k-steps (in flight
// UNDER compute), then converted+ds_written, ONE barrier. 4 barriers total.
// A-frags come straight from L2 (packed layout, 1KB/wave-instr); B-frags
// ds_read_b128 from the resident panel. 4 waves x (64 rows x 16 cols).
// ---------------------------------------------------------------------------
#define BN  16
#define QK  512           // k-extent per quarter
#define LDB 516           // padded LDS row stride (elems): 512 + 4

__global__ __launch_bounds__(256, 3) void gemm_kernel(
    const unsigned short* __restrict__ Xpk,  // packed A, 1MB, L2-resident
    const float* __restrict__ V,             // [16384][2048] fp32
    float* __restrict__ C) {                 // [256][16384] fp32
  __shared__ unsigned short Bs0[BN * LDB];   // 16512 B
  __shared__ unsigned short Bs1[BN * LDB];   // 16512 B
  const int t = threadIdx.x;
  const int lane = t & 63;
  const int w    = t >> 6;
  const int n0 = blockIdx.x * BN;

  // staging map: thread t -> V row sr (0..15), float col sc + g*64.
  // per wave instr: 4 rows x 256 B contiguous segments — coalesced.
  const int sr = t >> 4;
  const int sc = (t & 15) * 4;
  const float* Vp = V + (size_t)(n0 + sr) * DIM + sc;
  unsigned short* Bw0 = &Bs0[sr * LDB + sc];
  unsigned short* Bw1 = &Bs1[sr * LDB + sc];

  // fragment maps
  const int fr  = lane & 15;
  const int fq8 = (lane >> 4) * 8;
  const unsigned short* Ap = Xpk + (size_t)(w * 4) * 32768 + (size_t)lane * 8;

  f32x4 acc[4];
#pragma unroll
  for (int i = 0; i < 4; i++) acc[i] = (f32x4){0.f, 0.f, 0.f, 0.f};

  // ---- prologue: stage quarter 0 -> Bs0 ----
  {
    float4 vs[8];
#pragma unroll
    for (int g = 0; g < 8; g++) vs[g] = *(const float4*)(Vp + g * 64);
#pragma unroll
    for (int g = 0; g < 8; g++) {
      uint2 p; p.x = pk2(vs[g].x, vs[g].y); p.y = pk2(vs[g].z, vs[g].w);
      *(uint2*)(Bw0 + g * 64) = p;
    }
  }
  __syncthreads();

#pragma unroll
  for (int q = 0; q < 4; ++q) {
    const unsigned short* rb = (q & 1) ? Bs1 : Bs0;   // holds quarter q
    unsigned short*       wb = (q & 1) ? Bw0 : Bw1;   // gets quarter q+1
    const int kcb = q * 16;

    bf16x8 aE[4], aO[4], bE, bO;
    float4 vs[8];
    bE = *(const bf16x8*)&rb[fr * LDB + fq8];
#pragma unroll
    for (int i = 0; i < 4; ++i)
      aE[i] = *(const bf16x8*)(Ap + (size_t)i * 32768 + (size_t)kcb * 512);

#pragma unroll
    for (int j = 0; j < 16; j += 2) {
      // issue ONE next-quarter staging load per phase (8 over the quarter):
      // these fly under the MFMA stream, never waited on until quarter end.
      if (q < 3)
        vs[j >> 1] = *(const float4*)(Vp + (q + 1) * QK + (j >> 1) * 64);
      // odd-step frags (j+1)
      bO = *(const bf16x8*)&rb[fr * LDB + (j + 1) * 32 + fq8];
#pragma unroll
      for (int i = 0; i < 4; ++i)
        aO[i] = *(const bf16x8*)(Ap + (size_t)i * 32768 + (size_t)(kcb + j + 1) * 512);
#pragma unroll
      for (int i = 0; i < 4; ++i)
        acc[i] = __builtin_amdgcn_mfma_f32_16x16x32_bf16(aE[i], bE, acc[i], 0, 0, 0);
      if (j < 14) {  // even-step frags (j+2)
        bE = *(const bf16x8*)&rb[fr * LDB + (j + 2) * 32 + fq8];
#pragma unroll
        for (int i = 0; i < 4; ++i)
          aE[i] = *(const bf16x8*)(Ap + (size_t)i * 32768 + (size_t)(kcb + j + 2) * 512);
      }
#pragma unroll
      for (int i = 0; i < 4; ++i)
        acc[i] = __builtin_amdgcn_mfma_f32_16x16x32_bf16(aO[i], bO, acc[i], 0, 0, 0);
    }

    if (q < 3) {   // convert + write quarter q+1 (buffer free: last read q-1)
#pragma unroll
      for (int g = 0; g < 8; ++g) {
        uint2 p; p.x = pk2(vs[g].x, vs[g].y); p.y = pk2(vs[g].z, vs[g].w);
        *(uint2*)(wb + g * 64) = p;
      }
    }
    __syncthreads();   // quarter q+1 visible to all waves
  }

  // epilogue: C/D layout col=lane&15, row=(lane>>4)*4+reg  [m89/m91 verified]
  const int cr = (lane >> 4) * 4;
  const int cc = lane & 15;
#pragma unroll
  for (int i = 0; i < 4; i++)
#pragma unroll
    for (int r = 0; r < 4; r++)
      C[(size_t)(w * 64 + i * 16 + cr + r) * NMEM + (n0 + cc)] = acc[i][r];
}

// ---------------------------------------------------------------------------
// Kernel 3: per-row losses. One block of 1024 thr per sample.
// REGISTER-RESIDENT row: 16 floats/thread in 4 float4s (statically unrolled).
//  pass 1: masked row max + intra exp-sum over own bank (fused)
//  pass 2: tail histogram over [vmax-W, vmax], 2048 bins; widening fallback
//  pass 3: sum exp over bins > boundary; boundary bin resolved exactly
// ---------------------------------------------------------------------------
__global__ __launch_bounds__(1024) void row_loss_kernel(
    const float* __restrict__ logits,
    const int* __restrict__ labels, const int* __restrict__ cams,
    float* __restrict__ ce_out, float* __restrict__ lossk_out) {
  __shared__ float ovs[CCAM];
  __shared__ float wredA[16], wredB[16];
  __shared__ int   hist[NB2];       // 8 KB
  __shared__ int   pint[256];
  __shared__ float bl[512];
  __shared__ int   bcount;
  __shared__ int   bstar_s, cabove_s, totwin_s;
  __shared__ float vmax_s;

  const int b = blockIdx.x, t = threadIdx.x;
  const int lane = t & 63, wid = t >> 6;
  const int cam = cams[b], label = labels[b];
  const float* row = logits + (size_t)b * NMEM;

  if (t < CCAM) ovs[t] = row[t * PCLS + label];

  float4 rr[4];
#pragma unroll
  for (int i = 0; i < 4; i++) rr[i] = *(const float4*)(row + (size_t)(t + 1024 * i) * 4);

  // ---- pass 1: masked max + intra exp-sum (own bank, unmasked) ----
  float vmax = -1e30f, Si = 0.f;
#pragma unroll
  for (int i = 0; i < 4; i++) {
    const int base = (t + 1024 * i) * 4;
    const float xs[4] = {rr[i].x, rr[i].y, rr[i].z, rr[i].w};
#pragma unroll
    for (int e = 0; e < 4; e++) {
      const int n = base + e;
      const float x = xs[e];
      if ((n >> 11) == cam) Si += __expf(x * T_INV);
      if ((n & (PCLS - 1)) != label) vmax = fmaxf(vmax, x);
    }
  }
#pragma unroll
  for (int off = 32; off > 0; off >>= 1) {
    vmax = fmaxf(vmax, __shfl_down(vmax, off));
    Si  += __shfl_down(Si, off);
  }
  if (lane == 0) { wredA[wid] = vmax; wredB[wid] = Si; }
  __syncthreads();
  if (t == 0) {
    float m = -1e30f, s = 0.f;
    for (int i = 0; i < 16; i++) { m = fmaxf(m, wredA[i]); s += wredB[i]; }
    vmax_s = m;
    ce_out[b] = logf(s) - ovs[cam] * T_INV;
    bcount = 0;
  }
  __syncthreads();

  // ---- pass 2: tail histogram with widening fallback ----
  float W = 0.0625f;
  float lo = 0.f, scale = 0.f;
  for (int att = 0; att < 6; ++att) {
    __syncthreads();
    for (int i = t; i < NB2; i += 1024) hist[i] = 0;
    __syncthreads();
    lo = vmax_s - W; scale = (float)NB2 / W;
#pragma unroll
    for (int i = 0; i < 4; i++) {
      const int base = (t + 1024 * i) * 4;
      const float xs[4] = {rr[i].x, rr[i].y, rr[i].z, rr[i].w};
#pragma unroll
      for (int e = 0; e < 4; e++) {
        const int n = base + e;
        const float x = xs[e];
        if (((n & (PCLS - 1)) != label) && x >= lo)
          atomicAdd(&hist[binw(x, lo, scale)], 1);
      }
    }
    __syncthreads();
    if (t < 256) {
      int ps = 0;
#pragma unroll
      for (int i = 0; i < 8; i++) ps += hist[t * 8 + i];
      pint[t] = ps;
    }
    __syncthreads();
    if (t == 0) {
      int tot = 0;
      for (int i = 0; i < 256; i++) tot += pint[i];
      totwin_s = tot;
      if (tot >= KSEL) {
        int cum = 0, bstar = 0, cab = 0;
        for (int tc = 255; tc >= 0; tc--) {
          if (cum + pint[tc] >= KSEL) {
            for (int bi = tc * 8 + 7; bi >= tc * 8; bi--) {
              int h = hist[bi];
              if (cum + h >= KSEL) { bstar = bi; cab = cum; break; }
              cum += h;
            }
            break;
          }
          cum += pint[tc];
        }
        bstar_s = bstar; cabove_s = cab;
      }
    }
    __syncthreads();
    if (totwin_s >= KSEL) break;
    W *= 8.f;
  }
  const int bstar = bstar_s;

  // ---- pass 3: sum exp over bins > b*, collect boundary bin ----
  float S2 = 0.f;
#pragma unroll
  for (int i = 0; i < 4; i++) {
    const int base = (t + 1024 * i) * 4;
    const float xs[4] = {rr[i].x, rr[i].y, rr[i].z, rr[i].w};
#pragma unroll
    for (int e = 0; e < 4; e++) {
      const int n = base + e;
      const float x = xs[e];
      if (((n & (PCLS - 1)) != label) && x >= lo) {
        const int bin = binw(x, lo, scale);
        if (bin > bstar) S2 += __expf(x * T_INV);
        else if (bin == bstar) {
          int p = atomicAdd(&bcount, 1);
          if (p < 512) bl[p] = x;
        }
      }
    }
  }
#pragma unroll
  for (int off = 32; off > 0; off >>= 1) S2 += __shfl_down(S2, off);
  if (lane == 0) wredB[wid] = S2;
  __syncthreads();

  if (t == 0) {
    float S2tot = 0.f;
    for (int i = 0; i < 16; i++) S2tot += wredB[i];
    const int need = KSEL - cabove_s;
    const int bc = min(bcount, 512);
    for (int r = 0; r < need; r++) {         // exact top-(need) of boundary bin
      float mx = -1e30f; int mi = 0;
      for (int i = 0; i < bc; i++) if (bl[i] > mx) { mx = bl[i]; mi = i; }
      S2tot += __expf(mx * T_INV);
      bl[mi] = -1e30f;
    }
    float sumo = 0.f;
#pragma unroll
    for (int c = 0; c < CCAM; c++) { S2tot += __expf(ovs[c] * T_INV); sumo += ovs[c]; }
    lossk_out[b] = logf(S2tot) - (sumo * T_INV) * (1.0f / CCAM);
  }
}

// ---------------------------------------------------------------------------
// Kernel 4: deterministic per-camera segment means -> 2 scalars.
// ---------------------------------------------------------------------------
__global__ __launch_bounds__(256) void finalize_kernel(
    const float* __restrict__ ce, const float* __restrict__ lossk,
    const int* __restrict__ cams, float* __restrict__ out) {
  __shared__ float ce_s[BATCH], lk_s[BATCH];
  __shared__ int   cam_s[BATCH];
  __shared__ float si[CCAM], sk[CCAM], cnt[CCAM];
  const int t = threadIdx.x;
  ce_s[t]  = ce[t];
  lk_s[t]  = lossk[t];
  cam_s[t] = cams[t];
  __syncthreads();
  if (t < CCAM) {
    float a = 0.f, b = 0.f; int n = 0;
    for (int i = 0; i < BATCH; i++) {
      if (cam_s[i] == t) { a += ce_s[i]; b += lk_s[i]; n++; }
    }
    si[t] = a; sk[t] = b; cnt[t] = (float)n;
  }
  __syncthreads();
  if (t == 0) {
    float li = 0.f, lk = 0.f;
    for (int c = 0; c < CCAM; c++) {
      if (cnt[c] > 0.f) { li += si[c] / cnt[c]; lk += sk[c] / cnt[c]; }
    }
    out[0] = li;
    out[1] = 0.5f * lk;
  }
}

// ---------------------------------------------------------------------------
extern "C" void kernel_launch(void* const* d_in, const int* in_sizes, int n_in,
                              void* d_out, int out_size, void* d_ws, size_t ws_size,
                              hipStream_t stream) {
  const float* inputs = (const float*)d_in[0];   // [256][2048]
  const int*   labels = (const int*)d_in[1];     // [256]
  const int*   cams   = (const int*)d_in[2];     // [256]
  const float* tempV  = (const float*)d_in[3];   // [16384][2048]
  float* out = (float*)d_out;

  char* ws = (char*)d_ws;
  unsigned short* xpk = (unsigned short*)ws;                       // 1 MB packed A
  float* logits       = (float*)(ws + (1u << 20));                 // 16 MB
  float* ce           = (float*)(ws + (1u << 20) + (16u << 20));   // 1 KB
  float* lossk        = (float*)(ws + (1u << 20) + (16u << 20) + 1024);

  norm_cast_kernel<<<BATCH, 256, 0, stream>>>(inputs, xpk);
  gemm_kernel<<<NMEM / BN, 256, 0, stream>>>(xpk, tempV, logits);
  row_loss_kernel<<<BATCH, 1024, 0, stream>>>(logits, labels, cams, ce, lossk);
  finalize_kernel<<<1, 256, 0, stream>>>(ce, lossk, cams, out);
}

// Round 5
// 256.751 us; speedup vs baseline: 1.1159x; 1.0526x over previous
//
#include <hip/hip_runtime.h>
#include <hip/hip_bf16.h>

// Problem constants
#define BATCH 256
#define DIM   2048
#define NMEM  16384   // C_CAM * P
#define PCLS  2048
#define CCAM  8
#define KSEL  50
#define T_INV 14.285714285714285714f   // 1 / 0.07
#define NB2   2048    // tail-histogram bins

typedef __bf16 bf16x8 __attribute__((ext_vector_type(8)));
typedef float  f32x4  __attribute__((ext_vector_type(4)));

static __device__ __forceinline__ unsigned int f2bf(float f) {
  unsigned int u = __float_as_uint(f);
  return (u + 0x7FFFu + ((u >> 16) & 1u)) >> 16;   // RNE truncate to bf16
}
static __device__ __forceinline__ unsigned int pk2(float lo, float hi) {
  return f2bf(lo) | (f2bf(hi) << 16);
}
// tail-window binning
static __device__ __forceinline__ int binw(float x, float lo, float scale) {
  int b = (int)((x - lo) * scale);
  return b > (NB2 - 1) ? (NB2 - 1) : b;
}

// Packed-A addressing (kept from R4: bank-conflict-free, coalesced frag loads)
// [mf(16)][kc(64)][lane(64)][8 elems]; lane = (r&15) | (((c>>3)&3)<<4)
static __device__ __forceinline__ size_t pa_idx(int r, int c) {
  return (size_t)(r >> 4) * (size_t)(64 * 8 * (DIM / 32))   // 32768 per mf
       + (size_t)(c >> 5) * 512
       + (size_t)(((r & 15) | (((c >> 3) & 3) << 4))) * 8
       + (size_t)(c & 7);
}

// ---------------------------------------------------------------------------
// Kernel 1: row-normalize inputs, cast to bf16, write A pre-packed (unchanged)
// ---------------------------------------------------------------------------
__global__ __launch_bounds__(256) void norm_cast_kernel(
    const float* __restrict__ in, unsigned short* __restrict__ xpk) {
  __shared__ float red[256];
  const int b = blockIdx.x, t = threadIdx.x;
  const float4* row = (const float4*)(in + (size_t)b * DIM);
  float4 a0 = row[t];
  float4 a1 = row[t + 256];
  float ss = a0.x*a0.x + a0.y*a0.y + a0.z*a0.z + a0.w*a0.w
           + a1.x*a1.x + a1.y*a1.y + a1.z*a1.z + a1.w*a1.w;
  red[t] = ss; __syncthreads();
  for (int s = 128; s > 0; s >>= 1) { if (t < s) red[t] += red[t + s]; __syncthreads(); }
  const float rn = rsqrtf(red[0]);
  ushort4 o0, o1;
  o0.x = (unsigned short)f2bf(a0.x*rn); o0.y = (unsigned short)f2bf(a0.y*rn);
  o0.z = (unsigned short)f2bf(a0.z*rn); o0.w = (unsigned short)f2bf(a0.w*rn);
  o1.x = (unsigned short)f2bf(a1.x*rn); o1.y = (unsigned short)f2bf(a1.y*rn);
  o1.z = (unsigned short)f2bf(a1.z*rn); o1.w = (unsigned short)f2bf(a1.w*rn);
  *(ushort4*)&xpk[pa_idx(b, 4 * t)]         = o0;
  *(ushort4*)&xpk[pa_idx(b, 4 * (t + 256))] = o1;
}

// ---------------------------------------------------------------------------
// Kernel 2: logits = x(bf16) @ tempV^T — VMEM-FIFO-clean chunked pipeline.
// R0-R4 post-mortem: every structure mixed MFMA-feeding loads with V-stream
// loads in one wave's VMEM FIFO; vmcnt is FIFO-ordered, so each A-wait
// drained V's HBM latency -> invariant ~85-105 us. Here MFMA operands come
// ONLY from registers (A, loaded a full chunk ahead) and LDS (B); global
// loads drain at exactly ONE point per chunk (the barrier), aged >= 1 chunk.
//  - BM=128, BN=64, BK=64 chunks (32 chunks, 1 barrier each).
//  - wave = 32 rows x 64 cols: 8 MFMA / k-step, A:MFMA = 1:4.
//  - B LDS stored in MFMA-FRAGMENT ORDER [frag(8)][lane(64)][8]: ds_read_b128
//    is 64 lanes x consecutive 16B -> structurally conflict-free.
//  - A-frags from packed xpk (L2-hot), ping-pong reg sets, 1 chunk ahead.
// ---------------------------------------------------------------------------
#define BMH 128
#define BNW 64
#define BKC 64
#define NCH (DIM / BKC)   // 32

__global__ __launch_bounds__(256, 2) void gemm_kernel(
    const unsigned short* __restrict__ Xpk,  // packed A, 1MB, L2-resident
    const float* __restrict__ V,             // [16384][2048] fp32
    float* __restrict__ C) {                 // [256][16384] fp32
  __shared__ __align__(16) unsigned short Bf[2][8][512];   // 16 KB
  const int t    = threadIdx.x;
  const int lane = t & 63;
  const int wid  = t >> 6;
  const int n0 = blockIdx.x * BNW;
  const int m0 = blockIdx.y * BMH;

  // V staging: thread t -> V row vr (0..63), 16 floats at col vq*16.
  const int vr = t >> 2;
  const int vq = t & 3;
  const float* Vp = V + (size_t)(n0 + vr) * DIM + vq * 16;
  // LDS frag-order targets: frag wf = (vr>>4)*2 + (vq>>1); lane slot
  // wl = 32*(vq&1) + (vr&15) covers q=2*(vq&1); +16 lanes covers q+1.
  const int wf = (vr >> 4) * 2 + (vq >> 1);
  const int wl = 32 * (vq & 1) + (vr & 15);

  // A-frag pointer: wave rows m0 + wid*32; mf_g(i) = (m0>>4) + wid*2 + i
  const unsigned short* Apk = Xpk + (size_t)((m0 >> 4) + wid * 2) * 32768
                                  + (size_t)lane * 8;

  f32x4 acc[2][4];
#pragma unroll
  for (int i = 0; i < 2; i++)
#pragma unroll
    for (int j = 0; j < 4; j++) acc[i][j] = (f32x4){0.f, 0.f, 0.f, 0.f};

  bf16x8 aE[4], aO[4];     // A-frag ping-pong sets: [i*2+s]
  float4 vE[4], vO[4];     // V staging ping-pong sets

#define LOADA(SET, ch)                                                        \
  {                                                                           \
    const int ck_ = (ch);                                                     \
    _Pragma("unroll")                                                         \
    for (int i = 0; i < 2; ++i)                                               \
      _Pragma("unroll")                                                       \
      for (int s = 0; s < 2; ++s)                                             \
        SET[i * 2 + s] = *(const bf16x8*)(Apk + (size_t)i * 32768             \
                                              + (size_t)(ck_ * 2 + s) * 512); \
  }
#define LOADV(VS, ch)                                                         \
  {                                                                           \
    const int ck_ = (ch);                                                     \
    _Pragma("unroll")                                                         \
    for (int g = 0; g < 4; ++g)                                               \
      VS[g] = *(const float4*)(Vp + ck_ * BKC + g * 4);                       \
  }
#define WRITEB(buf, VS)                                                       \
  {                                                                           \
    uint4 u0_, u1_;                                                           \
    u0_.x = pk2(VS[0].x, VS[0].y); u0_.y = pk2(VS[0].z, VS[0].w);             \
    u0_.z = pk2(VS[1].x, VS[1].y); u0_.w = pk2(VS[1].z, VS[1].w);             \
    u1_.x = pk2(VS[2].x, VS[2].y); u1_.y = pk2(VS[2].z, VS[2].w);             \
    u1_.z = pk2(VS[3].x, VS[3].y); u1_.w = pk2(VS[3].z, VS[3].w);             \
    *(uint4*)&Bf[buf][wf][(size_t)wl * 8]        = u0_;                       \
    *(uint4*)&Bf[buf][wf][(size_t)(wl + 16) * 8] = u1_;                       \
  }
#define COMPUTE(buf, ASET)                                                    \
  {                                                                           \
    _Pragma("unroll")                                                         \
    for (int s = 0; s < 2; ++s) {                                             \
      bf16x8 bF_[4];                                                          \
      _Pragma("unroll")                                                       \
      for (int j = 0; j < 4; ++j)                                             \
        bF_[j] = *(const bf16x8*)&Bf[buf][j * 2 + s][(size_t)lane * 8];       \
      _Pragma("unroll")                                                       \
      for (int i = 0; i < 2; ++i)                                             \
        _Pragma("unroll")                                                     \
        for (int j = 0; j < 4; ++j)                                           \
          acc[i][j] = __builtin_amdgcn_mfma_f32_16x16x32_bf16(                \
              ASET[i * 2 + s], bF_[j], acc[i][j], 0, 0, 0);                   \
    }                                                                         \
  }

  // ---- prologue ----
  LOADA(aE, 0); LOADV(vE, 0);
  WRITEB(0, vE);                 // waits vE only (nothing older in FIFO)
  LOADA(aO, 1); LOADV(vO, 1);
  __syncthreads();               // buf0 = B(0) ready; aE arrived

#pragma unroll 1
  for (int it = 0; it < NCH / 2; ++it) {
    const int ch = 2 * it;
    // ---- even chunk ch: compute from aE + buf0 ----
    LOADV(vE, min(ch + 2, NCH - 1));       // refill vE (written last phase)
    COMPUTE(0, aE);
    WRITEB(1, vO);                         // vO aged 1 chunk
    LOADA(aE, min(ch + 2, NCH - 1));       // A for chunk ch+2
    __syncthreads();                       // buf1 = B(ch+1) ready
    // ---- odd chunk ch+1: compute from aO + buf1 ----
    LOADV(vO, min(ch + 3, NCH - 1));
    COMPUTE(1, aO);
    WRITEB(0, vE);                         // buf0 <- B(ch+2)
    LOADA(aO, min(ch + 3, NCH - 1));       // A for chunk ch+3
    __syncthreads();
  }

  // epilogue: C/D layout col=lane&15, row=(lane>>4)*4+reg  [m89/m91 verified]
  const int cr = (lane >> 4) * 4;
  const int cc = lane & 15;
#pragma unroll
  for (int i = 0; i < 2; i++)
#pragma unroll
    for (int j = 0; j < 4; j++)
#pragma unroll
      for (int r = 0; r < 4; r++)
        C[(size_t)(m0 + wid * 32 + i * 16 + cr + r) * NMEM + (n0 + j * 16 + cc)] =
            acc[i][j][r];
#undef LOADA
#undef LOADV
#undef WRITEB
#undef COMPUTE
}

// ---------------------------------------------------------------------------
// Kernel 3: per-row losses (unchanged from R4 for attribution).
// ---------------------------------------------------------------------------
__global__ __launch_bounds__(1024) void row_loss_kernel(
    const float* __restrict__ logits,
    const int* __restrict__ labels, const int* __restrict__ cams,
    float* __restrict__ ce_out, float* __restrict__ lossk_out) {
  __shared__ float ovs[CCAM];
  __shared__ float wredA[16], wredB[16];
  __shared__ int   hist[NB2];       // 8 KB
  __shared__ int   pint[256];
  __shared__ float bl[512];
  __shared__ int   bcount;
  __shared__ int   bstar_s, cabove_s, totwin_s;
  __shared__ float vmax_s;

  const int b = blockIdx.x, t = threadIdx.x;
  const int lane = t & 63, wid = t >> 6;
  const int cam = cams[b], label = labels[b];
  const float* row = logits + (size_t)b * NMEM;

  if (t < CCAM) ovs[t] = row[t * PCLS + label];

  float4 rr[4];
#pragma unroll
  for (int i = 0; i < 4; i++) rr[i] = *(const float4*)(row + (size_t)(t + 1024 * i) * 4);

  // ---- pass 1: masked max + intra exp-sum (own bank, unmasked) ----
  float vmax = -1e30f, Si = 0.f;
#pragma unroll
  for (int i = 0; i < 4; i++) {
    const int base = (t + 1024 * i) * 4;
    const float xs[4] = {rr[i].x, rr[i].y, rr[i].z, rr[i].w};
#pragma unroll
    for (int e = 0; e < 4; e++) {
      const int n = base + e;
      const float x = xs[e];
      if ((n >> 11) == cam) Si += __expf(x * T_INV);
      if ((n & (PCLS - 1)) != label) vmax = fmaxf(vmax, x);
    }
  }
#pragma unroll
  for (int off = 32; off > 0; off >>= 1) {
    vmax = fmaxf(vmax, __shfl_down(vmax, off));
    Si  += __shfl_down(Si, off);
  }
  if (lane == 0) { wredA[wid] = vmax; wredB[wid] = Si; }
  __syncthreads();
  if (t == 0) {
    float m = -1e30f, s = 0.f;
    for (int i = 0; i < 16; i++) { m = fmaxf(m, wredA[i]); s += wredB[i]; }
    vmax_s = m;
    ce_out[b] = logf(s) - ovs[cam] * T_INV;
    bcount = 0;
  }
  __syncthreads();

  // ---- pass 2: tail histogram with widening fallback ----
  float W = 0.0625f;
  float lo = 0.f, scale = 0.f;
  for (int att = 0; att < 6; ++att) {
    __syncthreads();
    for (int i = t; i < NB2; i += 1024) hist[i] = 0;
    __syncthreads();
    lo = vmax_s - W; scale = (float)NB2 / W;
#pragma unroll
    for (int i = 0; i < 4; i++) {
      const int base = (t + 1024 * i) * 4;
      const float xs[4] = {rr[i].x, rr[i].y, rr[i].z, rr[i].w};
#pragma unroll
      for (int e = 0; e < 4; e++) {
        const int n = base + e;
        const float x = xs[e];
        if (((n & (PCLS - 1)) != label) && x >= lo)
          atomicAdd(&hist[binw(x, lo, scale)], 1);
      }
    }
    __syncthreads();
    if (t < 256) {
      int ps = 0;
#pragma unroll
      for (int i = 0; i < 8; i++) ps += hist[t * 8 + i];
      pint[t] = ps;
    }
    __syncthreads();
    if (t == 0) {
      int tot = 0;
      for (int i = 0; i < 256; i++) tot += pint[i];
      totwin_s = tot;
      if (tot >= KSEL) {
        int cum = 0, bstar = 0, cab = 0;
        for (int tc = 255; tc >= 0; tc--) {
          if (cum + pint[tc] >= KSEL) {
            for (int bi = tc * 8 + 7; bi >= tc * 8; bi--) {
              int h = hist[bi];
              if (cum + h >= KSEL) { bstar = bi; cab = cum; break; }
              cum += h;
            }
            break;
          }
          cum += pint[tc];
        }
        bstar_s = bstar; cabove_s = cab;
      }
    }
    __syncthreads();
    if (totwin_s >= KSEL) break;
    W *= 8.f;
  }
  const int bstar = bstar_s;

  // ---- pass 3: sum exp over bins > b*, collect boundary bin ----
  float S2 = 0.f;
#pragma unroll
  for (int i = 0; i < 4; i++) {
    const int base = (t + 1024 * i) * 4;
    const float xs[4] = {rr[i].x, rr[i].y, rr[i].z, rr[i].w};
#pragma unroll
    for (int e = 0; e < 4; e++) {
      const int n = base + e;
      const float x = xs[e];
      if (((n & (PCLS - 1)) != label) && x >= lo) {
        const int bin = binw(x, lo, scale);
        if (bin > bstar) S2 += __expf(x * T_INV);
        else if (bin == bstar) {
          int p = atomicAdd(&bcount, 1);
          if (p < 512) bl[p] = x;
        }
      }
    }
  }
#pragma unroll
  for (int off = 32; off > 0; off >>= 1) S2 += __shfl_down(S2, off);
  if (lane == 0) wredB[wid] = S2;
  __syncthreads();

  if (t == 0) {
    float S2tot = 0.f;
    for (int i = 0; i < 16; i++) S2tot += wredB[i];
    const int need = KSEL - cabove_s;
    const int bc = min(bcount, 512);
    for (int r = 0; r < need; r++) {         // exact top-(need) of boundary bin
      float mx = -1e30f; int mi = 0;
      for (int i = 0; i < bc; i++) if (bl[i] > mx) { mx = bl[i]; mi = i; }
      S2tot += __expf(mx * T_INV);
      bl[mi] = -1e30f;
    }
    float sumo = 0.f;
#pragma unroll
    for (int c = 0; c < CCAM; c++) { S2tot += __expf(ovs[c] * T_INV); sumo += ovs[c]; }
    lossk_out[b] = logf(S2tot) - (sumo * T_INV) * (1.0f / CCAM);
  }
}

// ---------------------------------------------------------------------------
// Kernel 4: deterministic per-camera segment means -> 2 scalars.
// ---------------------------------------------------------------------------
__global__ __launch_bounds__(256) void finalize_kernel(
    const float* __restrict__ ce, const float* __restrict__ lossk,
    const int* __restrict__ cams, float* __restrict__ out) {
  __shared__ float ce_s[BATCH], lk_s[BATCH];
  __shared__ int   cam_s[BATCH];
  __shared__ float si[CCAM], sk[CCAM], cnt[CCAM];
  const int t = threadIdx.x;
  ce_s[t]  = ce[t];
  lk_s[t]  = lossk[t];
  cam_s[t] = cams[t];
  __syncthreads();
  if (t < CCAM) {
    float a = 0.f, b = 0.f; int n = 0;
    for (int i = 0; i < BATCH; i++) {
      if (cam_s[i] == t) { a += ce_s[i]; b += lk_s[i]; n++; }
    }
    si[t] = a; sk[t] = b; cnt[t] = (float)n;
  }
  __syncthreads();
  if (t == 0) {
    float li = 0.f, lk = 0.f;
    for (int c = 0; c < CCAM; c++) {
      if (cnt[c] > 0.f) { li += si[c] / cnt[c]; lk += sk[c] / cnt[c]; }
    }
    out[0] = li;
    out[1] = 0.5f * lk;
  }
}

// ---------------------------------------------------------------------------
extern "C" void kernel_launch(void* const* d_in, const int* in_sizes, int n_in,
                              void* d_out, int out_size, void* d_ws, size_t ws_size,
                              hipStream_t stream) {
  const float* inputs = (const float*)d_in[0];   // [256][2048]
  const int*   labels = (const int*)d_in[1];     // [256]
  const int*   cams   = (const int*)d_in[2];     // [256]
  const float* tempV  = (const float*)d_in[3];   // [16384][2048]
  float* out = (float*)d_out;

  char* ws = (char*)d_ws;
  unsigned short* xpk = (unsigned short*)ws;                       // 1 MB packed A
  float* logits       = (float*)(ws + (1u << 20));                 // 16 MB
  float* ce           = (float*)(ws + (1u << 20) + (16u << 20));   // 1 KB
  float* lossk        = (float*)(ws + (1u << 20) + (16u << 20) + 1024);

  norm_cast_kernel<<<BATCH, 256, 0, stream>>>(inputs, xpk);
  gemm_kernel<<<dim3(NMEM / BNW, BATCH / BMH), 256, 0, stream>>>(xpk, tempV, logits);
  row_loss_kernel<<<BATCH, 1024, 0, stream>>>(logits, labels, cams, ce, lossk);
  finalize_kernel<<<1, 256, 0, stream>>>(ce, lossk, cams, out);
}